// Round 13
// baseline (306.695 us; speedup 1.0000x reference)
//
#include <hip/hip_runtime.h>
#include <stdint.h>

// Quantized linear (distiller RangeLinearQuantParamLayerWrapper):
//   maxabs(x), maxabs(W) -> int8 quantize -> exact i8 GEMM (int32 accum)
//   -> maxabs(accum) -> requantize -> dequantize f32.
//
// R12: GEMM rescaled to 128x128 tiles / 4-wave (256-thr) blocks so TWO
// blocks fit per CU (LDS 64 KB/block, launch_bounds(256,2), VGPR~130 < 256
// cap). Theory: R4's 1-block/CU puts all 8 waves in one barrier domain ->
// LDS-read pipe (2300 cyc/K-tile) and MFMA pipe (2612 cyc) serialize
// (measured 4875 = sum). Two independent barrier domains per CU let one
// block's read-head overlap the other's MFMA-tail.
// Schedule/swizzle/vmcnt algebra byte-identical to R4 (proven).

using i32x4 = __attribute__((ext_vector_type(4))) int;

#define M_DIM 8192
#define N_DIM 4096
#define K_DIM 4096

#define BM 128
#define BN 128
#define BKB 128              // K-tile bytes (= i8 elements)
#define NKT (K_DIM / BKB)    // 32

// ---------------- scalar init ----------------
__global__ void k_init(unsigned* sc) {
    sc[0] = 0u;  // maxabs(x) bits
    sc[1] = 0u;  // maxabs(W) bits
    sc[2] = 0u;  // max|accum|
}

// ---------------- fused absmax over x and W ----------------
__global__ __launch_bounds__(256) void k_absmax2(const float4* __restrict__ x,
                                                 const float4* __restrict__ w,
                                                 unsigned* __restrict__ sc) {
    const bool isX = blockIdx.x < 2048;
    const float4* src = isX ? x : w;
    const int n4 = isX ? (M_DIM * K_DIM / 4) : (N_DIM * K_DIM / 4);
    const int brel = isX ? blockIdx.x : (blockIdx.x - 2048);
    const int nb = isX ? 2048 : 1024;
    unsigned m = 0;
    for (int i = brel * 256 + threadIdx.x; i < n4; i += nb * 256) {
        float4 v = src[i];
        unsigned a = __float_as_uint(v.x) & 0x7fffffffu;
        unsigned b = __float_as_uint(v.y) & 0x7fffffffu;
        unsigned c = __float_as_uint(v.z) & 0x7fffffffu;
        unsigned d = __float_as_uint(v.w) & 0x7fffffffu;
        m = max(m, max(max(a, b), max(c, d)));
    }
    for (int off = 32; off; off >>= 1)
        m = max(m, (unsigned)__shfl_xor((int)m, off));
    __shared__ unsigned wm[4];
    int ln = threadIdx.x & 63, wv = threadIdx.x >> 6;
    if (ln == 0) wm[wv] = m;
    __syncthreads();
    if (threadIdx.x == 0)
        atomicMax(sc + (isX ? 0 : 1), max(max(wm[0], wm[1]), max(wm[2], wm[3])));
}

// ---------------- fused symmetric int8 quantize of x and W ----------------
__global__ __launch_bounds__(256) void k_quant2(const float4* __restrict__ x,
                                                const float4* __restrict__ w,
                                                unsigned* __restrict__ xq,
                                                unsigned* __restrict__ wq,
                                                const unsigned* __restrict__ sc) {
    const bool isX = blockIdx.x < 2048;
    const float4* src = isX ? x : w;
    unsigned* dst = isX ? xq : wq;
    const int n4 = isX ? (M_DIM * K_DIM / 4) : (N_DIM * K_DIM / 4);
    const int brel = isX ? blockIdx.x : (blockIdx.x - 2048);
    const int nb = isX ? 2048 : 1024;
    const float scale = 127.0f / __uint_as_float(sc[isX ? 0 : 1]);
    for (int i = brel * 256 + threadIdx.x; i < n4; i += nb * 256) {
        float4 v = src[i];
        int q0 = min(127, max(-128, (int)rintf(v.x * scale)));
        int q1 = min(127, max(-128, (int)rintf(v.y * scale)));
        int q2 = min(127, max(-128, (int)rintf(v.z * scale)));
        int q3 = min(127, max(-128, (int)rintf(v.w * scale)));
        dst[i] = (unsigned)(q0 & 0xff) | ((unsigned)(q1 & 0xff) << 8) |
                 ((unsigned)(q2 & 0xff) << 16) | ((unsigned)(q3 & 0xff) << 24);
    }
}

// ---------------- i8 GEMM, 128^2 tile, 4 waves, 2 blocks/CU ----------------
// Cross-wave safety (barrier + counted vmcnt), identical algebra to R4:
//   A(kt+1) restaged @ P0; B(kt+2) restaged @ P1.
//   vmcnt(4) @ P1: outstanding B(kt+1),A(kt+1),B(kt+2)=12 -> oldest 8 forced
//   = tile kt+1 landed; B(kt+2) stays in flight.
__global__ __launch_bounds__(256, 2) void k_gemm(const char* __restrict__ Aq,
                                                 const char* __restrict__ Bq,
                                                 int* __restrict__ C,
                                                 unsigned* __restrict__ maxAcc) {
    __shared__ __align__(16) char lds[65536];   // lA[2][128][128] | lB[2][128][128]
    __shared__ int wmax[4];

    const int t = threadIdx.x;
    const int ln = t & 63;
    const int wv = t >> 6;     // 0..3
    const int wr = wv >> 1;    // wave M half (0..1): rows wr*64..+63
    const int wc = wv & 1;     // wave N half (0..1): cols wc*64..+63
    const int lr = ln & 15;
    const int lk = ln >> 4;

    // XCD-aware swizzle: 2048 wgs, 2048%8==0 -> bijective
    const int bid = blockIdx.x;
    const int swz = (bid & 7) * 256 + (bid >> 3);
    const int bx = swz & 31;   // N tile (32)
    const int by = swz >> 5;   // M tile (64)
    const int arow0 = by * BM;
    const int brow0 = bx * BN;

    // ds_read lane offsets: rows r = 16*frag + lr, so r&7 == lr&7 for all
    // frags -> swizzled chunk slot cs is frag-independent; kh=1 slot = cs^4.
    const int cs0 = lk ^ (lr & 7);
    const int aoff0 = (((wr << 6) + lr) << 7) + (cs0 << 4);
    const int aoff1 = aoff0 ^ 64;
    const int boff0 = (((wc << 6) + lr) << 7) + (cs0 << 4);
    const int boff1 = boff0 ^ 64;

    // stage lane voffsets (32-bit)
    int voffA[2], voffB[2];
#pragma unroll
    for (int it = 0; it < 2; ++it) {
        const int chunk = it * 256 + t;
        const int row = chunk >> 3;                   // 0..63 within half
        const int gc = (chunk & 7) ^ (row & 7);       // inverse swizzle on src
        voffA[it] = (arow0 + row) * 4096 + (gc << 4);
        voffB[it] = (brow0 + row) * 4096 + (gc << 4);
    }

    i32x4 acc[4][4];
#pragma unroll
    for (int i = 0; i < 4; ++i)
#pragma unroll
        for (int j = 0; j < 4; ++j) acc[i][j] = (i32x4)(0);

    auto STAGE = [&](int kt, int j) {  // j: 0,1 = A halves; 2,3 = B halves
        const int slot = kt & 1;
        const int koff = kt * 128 + (j & 1) * 262144;  // (j&1)*64rows*4096
        const bool isA = (j < 2);
        const char* gbase = isA ? Aq : Bq;
        const int* voff = isA ? voffA : voffB;
        char* lbase = lds + (isA ? 0 : 32768) + (slot << 14) + ((j & 1) << 13) + (wv << 10);
#pragma unroll
        for (int it = 0; it < 2; ++it) {
            const char* g = gbase + (unsigned)(voff[it] + koff);
            __builtin_amdgcn_global_load_lds(
                (const __attribute__((address_space(1))) void*)g,
                (__attribute__((address_space(3))) void*)(lbase + (it << 12)), 16, 0, 0);
        }
    };

    // ---- prologue: A(0), B(0), B(1); wait A0+B0 landed (B1 in flight) ----
    STAGE(0, 0); STAGE(0, 1); STAGE(0, 2); STAGE(0, 3);
    STAGE(1, 2); STAGE(1, 3);
    asm volatile("s_waitcnt vmcnt(4)" ::: "memory");
    __builtin_amdgcn_s_barrier();
    __builtin_amdgcn_sched_barrier(0);

    for (int kt = 0; kt < NKT; ++kt) {
        const int sl = (kt & 1) << 14;
        const char* pA0 = lds + sl + aoff0;
        const char* pA1 = lds + sl + aoff1;
        const char* pB0 = lds + 32768 + sl + boff0;
        const char* pB1 = lds + 32768 + sl + boff1;
        i32x4 a[2][2], b[4][2];

        // ========== P0: read a01 + b0123; stage A(kt+1); MFMA a01 x b ==========
#pragma unroll
        for (int mi = 0; mi < 2; ++mi) {
            a[mi][0] = *(const i32x4*)(pA0 + (mi << 11));
            a[mi][1] = *(const i32x4*)(pA1 + (mi << 11));
        }
#pragma unroll
        for (int ni = 0; ni < 4; ++ni) {
            b[ni][0] = *(const i32x4*)(pB0 + (ni << 11));
            b[ni][1] = *(const i32x4*)(pB1 + (ni << 11));
        }
        if (kt + 1 < NKT) { STAGE(kt + 1, 0); STAGE(kt + 1, 1); }
        __builtin_amdgcn_s_setprio(1);
#pragma unroll
        for (int kh = 0; kh < 2; ++kh)
#pragma unroll
            for (int mi = 0; mi < 2; ++mi)
#pragma unroll
                for (int ni = 0; ni < 4; ++ni)
                    acc[mi][ni] = __builtin_amdgcn_mfma_i32_16x16x64_i8(
                        a[mi][kh], b[ni][kh], acc[mi][ni], 0, 0, 0);
        __builtin_amdgcn_s_setprio(0);
        __builtin_amdgcn_s_barrier();
        __builtin_amdgcn_sched_barrier(0);

        // ========== P1: read a23; stage B(kt+2); vmcnt; MFMA a23 x b ==========
#pragma unroll
        for (int mi = 0; mi < 2; ++mi) {
            a[mi][0] = *(const i32x4*)(pA0 + ((mi + 2) << 11));
            a[mi][1] = *(const i32x4*)(pA1 + ((mi + 2) << 11));
        }
        if (kt + 2 < NKT) {
            STAGE(kt + 2, 2); STAGE(kt + 2, 3);
            asm volatile("s_waitcnt vmcnt(4)" ::: "memory");  // tile kt+1 landed
        } else {
            asm volatile("s_waitcnt vmcnt(0)" ::: "memory");  // tail drain
        }
        __builtin_amdgcn_s_setprio(1);
#pragma unroll
        for (int kh = 0; kh < 2; ++kh)
#pragma unroll
            for (int mi = 0; mi < 2; ++mi)
#pragma unroll
                for (int ni = 0; ni < 4; ++ni)
                    acc[mi + 2][ni] = __builtin_amdgcn_mfma_i32_16x16x64_i8(
                        a[mi][kh], b[ni][kh], acc[mi + 2][ni], 0, 0, 0);
        __builtin_amdgcn_s_setprio(0);
        __builtin_amdgcn_s_barrier();
        __builtin_amdgcn_sched_barrier(0);
    }

    // ---- epilogue: C write + |acc| max. C/D: col=lane&15, row=(lane>>4)*4+reg
    int amax = 0;
#pragma unroll
    for (int mi = 0; mi < 4; ++mi) {
#pragma unroll
        for (int ni = 0; ni < 4; ++ni) {
            const int row0 = arow0 + (wr << 6) + (mi << 4) + (lk << 2);
            const int col  = brow0 + (wc << 6) + (ni << 4) + lr;
            i32x4 v = acc[mi][ni];
#pragma unroll
            for (int j = 0; j < 4; ++j) {
                C[(size_t)(row0 + j) * N_DIM + col] = v[j];
                int a = v[j] < 0 ? -v[j] : v[j];
                amax = max(amax, a);
            }
        }
    }
    for (int off = 32; off; off >>= 1)
        amax = max(amax, __shfl_xor(amax, off));
    if (ln == 0) wmax[wv] = amax;
    __syncthreads();
    if (t == 0) {
        int m = max(max(wmax[0], wmax[1]), max(wmax[2], wmax[3]));
        atomicMax(maxAcc, (unsigned)m);
    }
}

// ---------------- requantize int32 accum -> f32 output, in place ----------------
__global__ __launch_bounds__(256) void k_requant(int4* __restrict__ buf, int n4,
                                                 const unsigned* __restrict__ sc) {
    const float maxX = __uint_as_float(sc[0]);
    const float maxW = __uint_as_float(sc[1]);
    const float maxA = (float)(int)sc[2];
    const float in_scale = 127.0f / maxX;
    const float w_scale  = 127.0f / maxW;
    const float accum_scale = in_scale * w_scale;
    const float requant = 127.0f / maxA;
    const float out_scale = requant * accum_scale;
    int stride = gridDim.x * blockDim.x;
    for (int i = blockIdx.x * blockDim.x + threadIdx.x; i < n4; i += stride) {
        int4 v = buf[i];
        float4 o;
        o.x = fminf(127.f, fmaxf(-128.f, rintf((float)v.x * requant))) / out_scale;
        o.y = fminf(127.f, fmaxf(-128.f, rintf((float)v.y * requant))) / out_scale;
        o.z = fminf(127.f, fmaxf(-128.f, rintf((float)v.z * requant))) / out_scale;
        o.w = fminf(127.f, fmaxf(-128.f, rintf((float)v.w * requant))) / out_scale;
        ((float4*)buf)[i] = o;
    }
}

extern "C" void kernel_launch(void* const* d_in, const int* in_sizes, int n_in,
                              void* d_out, int out_size, void* d_ws, size_t ws_size,
                              hipStream_t stream) {
    const float* x = (const float*)d_in[0];  // [8192, 4096]
    const float* W = (const float*)d_in[1];  // [4096, 4096]

    unsigned* sc = (unsigned*)d_ws;
    char* xq = (char*)d_ws + 256;
    char* wq = xq + (size_t)M_DIM * K_DIM;

    k_init<<<1, 1, 0, stream>>>(sc);
    k_absmax2<<<3072, 256, 0, stream>>>((const float4*)x, (const float4*)W, sc);
    k_quant2<<<3072, 256, 0, stream>>>((const float4*)x, (const float4*)W,
                                       (unsigned*)xq, (unsigned*)wq, sc);
    k_gemm<<<(M_DIM / BM) * (N_DIM / BN), 256, 0, stream>>>(xq, wq, (int*)d_out, sc + 2);
    k_requant<<<2048, 256, 0, stream>>>((int4*)d_out, M_DIM * N_DIM / 4, sc);
}

// Round 14
// 276.364 us; speedup vs baseline: 1.1098x; 1.1098x over previous
//
#include <hip/hip_runtime.h>
#include <stdint.h>

// Quantized linear (distiller RangeLinearQuantParamLayerWrapper):
//   maxabs(x), maxabs(W) -> int8 quantize -> exact i8 GEMM (int32 accum)
//   -> maxabs(accum) -> requantize -> dequantize f32.
//
// FINAL (R13 = R11 = R4): best measured configuration.
//   - split absmax/quant/requant elementwise kernels (fused spin-barrier
//     variants regressed 2x: R5 RMW-poll, R6 load-poll)
//   - GEMM: 256x256 tile, BK=128 i8, 8 waves, 16x16x64 i8 MFMA, 2-phase
//     counted-vmcnt schedule. Variations all regressed: 4-phase (R1),
//     1-barrier (R7), 32x32x32 (R8, bank conflicts), a47-tail (R9),
//     BK=64 (R10, VGPR spill), 128^2 2-blocks/CU (R12, 2x HBM fetch).
// Cross-wave safety:
//   A(kt+1) restaged @ P0 (prev P1's a47 reads consumed before its barrier)
//   B(kt+2) restaged @ P1 (P0's b reads consumed before P0's barrier)
//   vmcnt(4) @ P1: outstanding B(kt+1),A(kt+1),B(kt+2)=12 -> oldest 8 forced
//   = tile kt+1 landed; B(kt+2) stays in flight.

using i32x4 = __attribute__((ext_vector_type(4))) int;

#define M_DIM 8192
#define N_DIM 4096
#define K_DIM 4096

#define BM 256
#define BN 256
#define BKB 128              // K-tile bytes (= i8 elements)
#define NKT (K_DIM / BKB)    // 32

// ---------------- scalar init ----------------
__global__ void k_init(unsigned* sc) {
    sc[0] = 0u;  // maxabs(x) bits
    sc[1] = 0u;  // maxabs(W) bits
    sc[2] = 0u;  // max|accum|
}

// ---------------- fused absmax over x and W ----------------
__global__ __launch_bounds__(256) void k_absmax2(const float4* __restrict__ x,
                                                 const float4* __restrict__ w,
                                                 unsigned* __restrict__ sc) {
    const bool isX = blockIdx.x < 2048;
    const float4* src = isX ? x : w;
    const int n4 = isX ? (M_DIM * K_DIM / 4) : (N_DIM * K_DIM / 4);
    const int brel = isX ? blockIdx.x : (blockIdx.x - 2048);
    const int nb = isX ? 2048 : 1024;
    unsigned m = 0;
    for (int i = brel * 256 + threadIdx.x; i < n4; i += nb * 256) {
        float4 v = src[i];
        unsigned a = __float_as_uint(v.x) & 0x7fffffffu;
        unsigned b = __float_as_uint(v.y) & 0x7fffffffu;
        unsigned c = __float_as_uint(v.z) & 0x7fffffffu;
        unsigned d = __float_as_uint(v.w) & 0x7fffffffu;
        m = max(m, max(max(a, b), max(c, d)));
    }
    for (int off = 32; off; off >>= 1)
        m = max(m, (unsigned)__shfl_xor((int)m, off));
    __shared__ unsigned wm[4];
    int ln = threadIdx.x & 63, wv = threadIdx.x >> 6;
    if (ln == 0) wm[wv] = m;
    __syncthreads();
    if (threadIdx.x == 0)
        atomicMax(sc + (isX ? 0 : 1), max(max(wm[0], wm[1]), max(wm[2], wm[3])));
}

// ---------------- fused symmetric int8 quantize of x and W ----------------
__global__ __launch_bounds__(256) void k_quant2(const float4* __restrict__ x,
                                                const float4* __restrict__ w,
                                                unsigned* __restrict__ xq,
                                                unsigned* __restrict__ wq,
                                                const unsigned* __restrict__ sc) {
    const bool isX = blockIdx.x < 2048;
    const float4* src = isX ? x : w;
    unsigned* dst = isX ? xq : wq;
    const int n4 = isX ? (M_DIM * K_DIM / 4) : (N_DIM * K_DIM / 4);
    const int brel = isX ? blockIdx.x : (blockIdx.x - 2048);
    const int nb = isX ? 2048 : 1024;
    const float scale = 127.0f / __uint_as_float(sc[isX ? 0 : 1]);
    for (int i = brel * 256 + threadIdx.x; i < n4; i += nb * 256) {
        float4 v = src[i];
        int q0 = min(127, max(-128, (int)rintf(v.x * scale)));
        int q1 = min(127, max(-128, (int)rintf(v.y * scale)));
        int q2 = min(127, max(-128, (int)rintf(v.z * scale)));
        int q3 = min(127, max(-128, (int)rintf(v.w * scale)));
        dst[i] = (unsigned)(q0 & 0xff) | ((unsigned)(q1 & 0xff) << 8) |
                 ((unsigned)(q2 & 0xff) << 16) | ((unsigned)(q3 & 0xff) << 24);
    }
}

// ---------------- i8 GEMM, 256^2, 2-phase/K-tile, unpinned interior ----------------
__global__ __launch_bounds__(512, 2) void k_gemm(const char* __restrict__ Aq,
                                                 const char* __restrict__ Bq,
                                                 int* __restrict__ C,
                                                 unsigned* __restrict__ maxAcc) {
    __shared__ __align__(16) char lds[131072];
    __shared__ int wmax[8];

    const int t = threadIdx.x;
    const int ln = t & 63;
    const int wv = t >> 6;
    const int wr = wv >> 2;    // wave M half (0..1): rows wr*128..+127
    const int wc = wv & 3;     // wave N quarter (0..3): cols wc*64..+63
    const int lr = ln & 15;
    const int lk = ln >> 4;

    // XCD-aware swizzle: 512 wgs, 512%8==0 -> bijective
    const int bid = blockIdx.x;
    const int swz = (bid & 7) * 64 + (bid >> 3);
    const int bx = swz & 15;   // N tile (16)
    const int by = swz >> 4;   // M tile (32)
    const int arow0 = by * BM;
    const int brow0 = bx * BN;

    // ds_read lane offsets: rows r = 16*frag + lr, so r&7 == lr&7 for all
    // frags -> swizzled chunk slot cs is frag-independent; kh=1 slot = cs^4.
    const int cs0 = lk ^ (lr & 7);
    const int aoff0 = (((wr << 7) + lr) << 7) + (cs0 << 4);
    const int aoff1 = aoff0 ^ 64;
    const int boff0 = (((wc << 6) + lr) << 7) + (cs0 << 4);
    const int boff1 = boff0 ^ 64;

    // stage lane voffsets (32-bit)
    int voffA[2], voffB[2];
#pragma unroll
    for (int it = 0; it < 2; ++it) {
        const int chunk = it * 512 + (wv << 6) + ln;
        const int row = chunk >> 3;                   // 0..127 within half
        const int gc = (chunk & 7) ^ (row & 7);       // inverse swizzle on src
        voffA[it] = (arow0 + row) * 4096 + (gc << 4);
        voffB[it] = (brow0 + row) * 4096 + (gc << 4);
    }

    i32x4 acc[8][4];
#pragma unroll
    for (int i = 0; i < 8; ++i)
#pragma unroll
        for (int j = 0; j < 4; ++j) acc[i][j] = (i32x4)(0);

    auto STAGE = [&](int kt, int j) {  // j: 0,1 = A halves; 2,3 = B halves
        const int slot = kt & 1;
        const int koff = kt * 128 + (j & 1) * 524288;  // (j&1)*128rows*4096
        const bool isA = (j < 2);
        const char* gbase = isA ? Aq : Bq;
        const int* voff = isA ? voffA : voffB;
        char* lbase = lds + (isA ? 0 : 65536) + (slot << 15) + ((j & 1) << 14) + (wv << 10);
#pragma unroll
        for (int it = 0; it < 2; ++it) {
            const char* g = gbase + (unsigned)(voff[it] + koff);
            __builtin_amdgcn_global_load_lds(
                (const __attribute__((address_space(1))) void*)g,
                (__attribute__((address_space(3))) void*)(lbase + (it << 13)), 16, 0, 0);
        }
    };

    // ---- prologue: A(0), B(0), B(1); wait A0+B0 landed (B1 in flight) ----
    STAGE(0, 0); STAGE(0, 1); STAGE(0, 2); STAGE(0, 3);
    STAGE(1, 2); STAGE(1, 3);
    asm volatile("s_waitcnt vmcnt(4)" ::: "memory");
    __builtin_amdgcn_s_barrier();
    __builtin_amdgcn_sched_barrier(0);

    for (int kt = 0; kt < NKT; ++kt) {
        const int sl = (kt & 1) << 15;
        const char* pA0 = lds + sl + aoff0;
        const char* pA1 = lds + sl + aoff1;
        const char* pB0 = lds + 65536 + sl + boff0;
        const char* pB1 = lds + 65536 + sl + boff1;
        i32x4 a[4][2], b[4][2];

        // ========== P0: read a03 + b0123; stage A(kt+1); MFMA a03 x b ==========
#pragma unroll
        for (int mi = 0; mi < 4; ++mi) {
            a[mi][0] = *(const i32x4*)(pA0 + (mi << 11));
            a[mi][1] = *(const i32x4*)(pA1 + (mi << 11));
        }
#pragma unroll
        for (int ni = 0; ni < 4; ++ni) {
            b[ni][0] = *(const i32x4*)(pB0 + (ni << 11));
            b[ni][1] = *(const i32x4*)(pB1 + (ni << 11));
        }
        if (kt + 1 < NKT) { STAGE(kt + 1, 0); STAGE(kt + 1, 1); }
        __builtin_amdgcn_s_setprio(1);
#pragma unroll
        for (int kh = 0; kh < 2; ++kh)
#pragma unroll
            for (int mi = 0; mi < 4; ++mi)
#pragma unroll
                for (int ni = 0; ni < 4; ++ni)
                    acc[mi][ni] = __builtin_amdgcn_mfma_i32_16x16x64_i8(
                        a[mi][kh], b[ni][kh], acc[mi][ni], 0, 0, 0);
        __builtin_amdgcn_s_setprio(0);
        __builtin_amdgcn_s_barrier();
        __builtin_amdgcn_sched_barrier(0);

        // ========== P1: read a47; stage B(kt+2); vmcnt; MFMA a47 x b ==========
#pragma unroll
        for (int mi = 0; mi < 4; ++mi) {
            a[mi][0] = *(const i32x4*)(pA0 + ((mi + 4) << 11));
            a[mi][1] = *(const i32x4*)(pA1 + ((mi + 4) << 11));
        }
        if (kt + 2 < NKT) {
            STAGE(kt + 2, 2); STAGE(kt + 2, 3);
            asm volatile("s_waitcnt vmcnt(4)" ::: "memory");  // tile kt+1 landed
        } else {
            asm volatile("s_waitcnt vmcnt(0)" ::: "memory");  // tail drain
        }
        __builtin_amdgcn_s_setprio(1);
#pragma unroll
        for (int kh = 0; kh < 2; ++kh)
#pragma unroll
            for (int mi = 0; mi < 4; ++mi)
#pragma unroll
                for (int ni = 0; ni < 4; ++ni)
                    acc[mi + 4][ni] = __builtin_amdgcn_mfma_i32_16x16x64_i8(
                        a[mi][kh], b[ni][kh], acc[mi + 4][ni], 0, 0, 0);
        __builtin_amdgcn_s_setprio(0);
        __builtin_amdgcn_s_barrier();
        __builtin_amdgcn_sched_barrier(0);
    }

    // ---- epilogue: C write + |acc| max. C/D: col=lane&15, row=(lane>>4)*4+reg
    int amax = 0;
#pragma unroll
    for (int mi = 0; mi < 8; ++mi) {
#pragma unroll
        for (int ni = 0; ni < 4; ++ni) {
            const int row0 = arow0 + (wr << 7) + (mi << 4) + (lk << 2);
            const int col  = brow0 + (wc << 6) + (ni << 4) + lr;
            i32x4 v = acc[mi][ni];
#pragma unroll
            for (int j = 0; j < 4; ++j) {
                C[(size_t)(row0 + j) * N_DIM + col] = v[j];
                int a = v[j] < 0 ? -v[j] : v[j];
                amax = max(amax, a);
            }
        }
    }
    for (int off = 32; off; off >>= 1)
        amax = max(amax, __shfl_xor(amax, off));
    if (ln == 0) wmax[wv] = amax;
    __syncthreads();
    if (t == 0) {
        int m = wmax[0];
#pragma unroll
        for (int i = 1; i < 8; ++i) m = max(m, wmax[i]);
        atomicMax(maxAcc, (unsigned)m);
    }
}

// ---------------- requantize int32 accum -> f32 output, in place ----------------
__global__ __launch_bounds__(256) void k_requant(int4* __restrict__ buf, int n4,
                                                 const unsigned* __restrict__ sc) {
    const float maxX = __uint_as_float(sc[0]);
    const float maxW = __uint_as_float(sc[1]);
    const float maxA = (float)(int)sc[2];
    const float in_scale = 127.0f / maxX;
    const float w_scale  = 127.0f / maxW;
    const float accum_scale = in_scale * w_scale;
    const float requant = 127.0f / maxA;
    const float out_scale = requant * accum_scale;
    int stride = gridDim.x * blockDim.x;
    for (int i = blockIdx.x * blockDim.x + threadIdx.x; i < n4; i += stride) {
        int4 v = buf[i];
        float4 o;
        o.x = fminf(127.f, fmaxf(-128.f, rintf((float)v.x * requant))) / out_scale;
        o.y = fminf(127.f, fmaxf(-128.f, rintf((float)v.y * requant))) / out_scale;
        o.z = fminf(127.f, fmaxf(-128.f, rintf((float)v.z * requant))) / out_scale;
        o.w = fminf(127.f, fmaxf(-128.f, rintf((float)v.w * requant))) / out_scale;
        ((float4*)buf)[i] = o;
    }
}

extern "C" void kernel_launch(void* const* d_in, const int* in_sizes, int n_in,
                              void* d_out, int out_size, void* d_ws, size_t ws_size,
                              hipStream_t stream) {
    const float* x = (const float*)d_in[0];  // [8192, 4096]
    const float* W = (const float*)d_in[1];  // [4096, 4096]

    unsigned* sc = (unsigned*)d_ws;
    char* xq = (char*)d_ws + 256;
    char* wq = xq + (size_t)M_DIM * K_DIM;

    k_init<<<1, 1, 0, stream>>>(sc);
    k_absmax2<<<3072, 256, 0, stream>>>((const float4*)x, (const float4*)W, sc);
    k_quant2<<<3072, 256, 0, stream>>>((const float4*)x, (const float4*)W,
                                       (unsigned*)xq, (unsigned*)wq, sc);
    k_gemm<<<(M_DIM / BM) * (N_DIM / BN), 512, 0, stream>>>(xq, wq, (int*)d_out, sc + 2);
    k_requant<<<2048, 256, 0, stream>>>((int4*)d_out, M_DIM * N_DIM / 4, sc);
}

// Round 15
// 272.206 us; speedup vs baseline: 1.1267x; 1.0153x over previous
//
#include <hip/hip_runtime.h>
#include <stdint.h>

// Quantized linear (distiller RangeLinearQuantParamLayerWrapper):
//   maxabs(x), maxabs(W) -> int8 quantize -> exact i8 GEMM (int32 accum)
//   -> maxabs(accum) -> requantize -> dequantize f32.
//
// R14 = R13 (proven anchor: GEMM 130us, MfmaUtil 45%, 0 conflicts) with two
// elementwise fixes:
//   1) k_quant2 now writes uint4 (16B/lane) instead of u32 (4B/lane):
//      each thread quantizes 16 elements (4x float4 reads -> 1 uint4 store).
//   2) k_init launch replaced by hipMemsetAsync(sc,0,16) - one less dispatch.
// GEMM schedule unchanged (2-phase counted-vmcnt; all 6 structural variants
// regressed: 4-phase R1, 1-barrier R7, 32x32x32 R8, a47-tail R9, BK=64 R10,
// 128^2 R12; fused spin-barrier quant regressed 2x: R5/R6).

using i32x4 = __attribute__((ext_vector_type(4))) int;

#define M_DIM 8192
#define N_DIM 4096
#define K_DIM 4096

#define BM 256
#define BN 256
#define BKB 128              // K-tile bytes (= i8 elements)
#define NKT (K_DIM / BKB)    // 32

// ---------------- fused absmax over x and W ----------------
__global__ __launch_bounds__(256) void k_absmax2(const float4* __restrict__ x,
                                                 const float4* __restrict__ w,
                                                 unsigned* __restrict__ sc) {
    const bool isX = blockIdx.x < 2048;
    const float4* src = isX ? x : w;
    const int n4 = isX ? (M_DIM * K_DIM / 4) : (N_DIM * K_DIM / 4);
    const int brel = isX ? blockIdx.x : (blockIdx.x - 2048);
    const int nb = isX ? 2048 : 1024;
    unsigned m = 0;
    for (int i = brel * 256 + threadIdx.x; i < n4; i += nb * 256) {
        float4 v = src[i];
        unsigned a = __float_as_uint(v.x) & 0x7fffffffu;
        unsigned b = __float_as_uint(v.y) & 0x7fffffffu;
        unsigned c = __float_as_uint(v.z) & 0x7fffffffu;
        unsigned d = __float_as_uint(v.w) & 0x7fffffffu;
        m = max(m, max(max(a, b), max(c, d)));
    }
    for (int off = 32; off; off >>= 1)
        m = max(m, (unsigned)__shfl_xor((int)m, off));
    __shared__ unsigned wm[4];
    int ln = threadIdx.x & 63, wv = threadIdx.x >> 6;
    if (ln == 0) wm[wv] = m;
    __syncthreads();
    if (threadIdx.x == 0)
        atomicMax(sc + (isX ? 0 : 1), max(max(wm[0], wm[1]), max(wm[2], wm[3])));
}

// ---------------- fused symmetric int8 quantize of x and W ----------------
// 16 elements/thread/iter: 4x float4 loads -> 1 uint4 (16B) store.
__global__ __launch_bounds__(256) void k_quant2(const float4* __restrict__ x,
                                                const float4* __restrict__ w,
                                                uint4* __restrict__ xq,
                                                uint4* __restrict__ wq,
                                                const unsigned* __restrict__ sc) {
    const bool isX = blockIdx.x < 2048;
    const float4* src = isX ? x : w;
    uint4* dst = isX ? xq : wq;
    const int n16 = (isX ? (M_DIM * K_DIM) : (N_DIM * K_DIM)) / 16;
    const int brel = isX ? blockIdx.x : (blockIdx.x - 2048);
    const int nb = isX ? 2048 : 1024;
    const float scale = 127.0f / __uint_as_float(sc[isX ? 0 : 1]);

    auto pack = [&](float4 v) -> unsigned {
        int q0 = min(127, max(-128, (int)rintf(v.x * scale)));
        int q1 = min(127, max(-128, (int)rintf(v.y * scale)));
        int q2 = min(127, max(-128, (int)rintf(v.z * scale)));
        int q3 = min(127, max(-128, (int)rintf(v.w * scale)));
        return (unsigned)(q0 & 0xff) | ((unsigned)(q1 & 0xff) << 8) |
               ((unsigned)(q2 & 0xff) << 16) | ((unsigned)(q3 & 0xff) << 24);
    };

    for (int i = brel * 256 + threadIdx.x; i < n16; i += nb * 256) {
        const float4* s = src + i * 4;
        uint4 o;
        o.x = pack(s[0]);
        o.y = pack(s[1]);
        o.z = pack(s[2]);
        o.w = pack(s[3]);
        dst[i] = o;
    }
}

// ---------------- i8 GEMM, 256^2, 2-phase/K-tile, unpinned interior ----------------
// Cross-wave safety (barrier + counted vmcnt):
//   A(kt+1) restaged @ P0 (prev P1's a47 reads consumed before its barrier)
//   B(kt+2) restaged @ P1 (P0's b reads consumed before P0's barrier)
//   vmcnt(4) @ P1: outstanding B(kt+1),A(kt+1),B(kt+2)=12 -> oldest 8 forced
//   = tile kt+1 landed; B(kt+2) stays in flight.
__global__ __launch_bounds__(512, 2) void k_gemm(const char* __restrict__ Aq,
                                                 const char* __restrict__ Bq,
                                                 int* __restrict__ C,
                                                 unsigned* __restrict__ maxAcc) {
    __shared__ __align__(16) char lds[131072];
    __shared__ int wmax[8];

    const int t = threadIdx.x;
    const int ln = t & 63;
    const int wv = t >> 6;
    const int wr = wv >> 2;    // wave M half (0..1): rows wr*128..+127
    const int wc = wv & 3;     // wave N quarter (0..3): cols wc*64..+63
    const int lr = ln & 15;
    const int lk = ln >> 4;

    // XCD-aware swizzle: 512 wgs, 512%8==0 -> bijective
    const int bid = blockIdx.x;
    const int swz = (bid & 7) * 64 + (bid >> 3);
    const int bx = swz & 15;   // N tile (16)
    const int by = swz >> 4;   // M tile (32)
    const int arow0 = by * BM;
    const int brow0 = bx * BN;

    // ds_read lane offsets: rows r = 16*frag + lr, so r&7 == lr&7 for all
    // frags -> swizzled chunk slot cs is frag-independent; kh=1 slot = cs^4.
    const int cs0 = lk ^ (lr & 7);
    const int aoff0 = (((wr << 7) + lr) << 7) + (cs0 << 4);
    const int aoff1 = aoff0 ^ 64;
    const int boff0 = (((wc << 6) + lr) << 7) + (cs0 << 4);
    const int boff1 = boff0 ^ 64;

    // stage lane voffsets (32-bit)
    int voffA[2], voffB[2];
#pragma unroll
    for (int it = 0; it < 2; ++it) {
        const int chunk = it * 512 + (wv << 6) + ln;
        const int row = chunk >> 3;                   // 0..127 within half
        const int gc = (chunk & 7) ^ (row & 7);       // inverse swizzle on src
        voffA[it] = (arow0 + row) * 4096 + (gc << 4);
        voffB[it] = (brow0 + row) * 4096 + (gc << 4);
    }

    i32x4 acc[8][4];
#pragma unroll
    for (int i = 0; i < 8; ++i)
#pragma unroll
        for (int j = 0; j < 4; ++j) acc[i][j] = (i32x4)(0);

    auto STAGE = [&](int kt, int j) {  // j: 0,1 = A halves; 2,3 = B halves
        const int slot = kt & 1;
        const int koff = kt * 128 + (j & 1) * 524288;  // (j&1)*128rows*4096
        const bool isA = (j < 2);
        const char* gbase = isA ? Aq : Bq;
        const int* voff = isA ? voffA : voffB;
        char* lbase = lds + (isA ? 0 : 65536) + (slot << 15) + ((j & 1) << 14) + (wv << 10);
#pragma unroll
        for (int it = 0; it < 2; ++it) {
            const char* g = gbase + (unsigned)(voff[it] + koff);
            __builtin_amdgcn_global_load_lds(
                (const __attribute__((address_space(1))) void*)g,
                (__attribute__((address_space(3))) void*)(lbase + (it << 13)), 16, 0, 0);
        }
    };

    // ---- prologue: A(0), B(0), B(1); wait A0+B0 landed (B1 in flight) ----
    STAGE(0, 0); STAGE(0, 1); STAGE(0, 2); STAGE(0, 3);
    STAGE(1, 2); STAGE(1, 3);
    asm volatile("s_waitcnt vmcnt(4)" ::: "memory");
    __builtin_amdgcn_s_barrier();
    __builtin_amdgcn_sched_barrier(0);

    for (int kt = 0; kt < NKT; ++kt) {
        const int sl = (kt & 1) << 15;
        const char* pA0 = lds + sl + aoff0;
        const char* pA1 = lds + sl + aoff1;
        const char* pB0 = lds + 65536 + sl + boff0;
        const char* pB1 = lds + 65536 + sl + boff1;
        i32x4 a[4][2], b[4][2];

        // ========== P0: read a03 + b0123; stage A(kt+1); MFMA a03 x b ==========
#pragma unroll
        for (int mi = 0; mi < 4; ++mi) {
            a[mi][0] = *(const i32x4*)(pA0 + (mi << 11));
            a[mi][1] = *(const i32x4*)(pA1 + (mi << 11));
        }
#pragma unroll
        for (int ni = 0; ni < 4; ++ni) {
            b[ni][0] = *(const i32x4*)(pB0 + (ni << 11));
            b[ni][1] = *(const i32x4*)(pB1 + (ni << 11));
        }
        if (kt + 1 < NKT) { STAGE(kt + 1, 0); STAGE(kt + 1, 1); }
        __builtin_amdgcn_s_setprio(1);
#pragma unroll
        for (int kh = 0; kh < 2; ++kh)
#pragma unroll
            for (int mi = 0; mi < 4; ++mi)
#pragma unroll
                for (int ni = 0; ni < 4; ++ni)
                    acc[mi][ni] = __builtin_amdgcn_mfma_i32_16x16x64_i8(
                        a[mi][kh], b[ni][kh], acc[mi][ni], 0, 0, 0);
        __builtin_amdgcn_s_setprio(0);
        __builtin_amdgcn_s_barrier();
        __builtin_amdgcn_sched_barrier(0);

        // ========== P1: read a47; stage B(kt+2); vmcnt; MFMA a47 x b ==========
#pragma unroll
        for (int mi = 0; mi < 4; ++mi) {
            a[mi][0] = *(const i32x4*)(pA0 + ((mi + 4) << 11));
            a[mi][1] = *(const i32x4*)(pA1 + ((mi + 4) << 11));
        }
        if (kt + 2 < NKT) {
            STAGE(kt + 2, 2); STAGE(kt + 2, 3);
            asm volatile("s_waitcnt vmcnt(4)" ::: "memory");  // tile kt+1 landed
        } else {
            asm volatile("s_waitcnt vmcnt(0)" ::: "memory");  // tail drain
        }
        __builtin_amdgcn_s_setprio(1);
#pragma unroll
        for (int kh = 0; kh < 2; ++kh)
#pragma unroll
            for (int mi = 0; mi < 4; ++mi)
#pragma unroll
                for (int ni = 0; ni < 4; ++ni)
                    acc[mi + 4][ni] = __builtin_amdgcn_mfma_i32_16x16x64_i8(
                        a[mi][kh], b[ni][kh], acc[mi + 4][ni], 0, 0, 0);
        __builtin_amdgcn_s_setprio(0);
        __builtin_amdgcn_s_barrier();
        __builtin_amdgcn_sched_barrier(0);
    }

    // ---- epilogue: C write + |acc| max. C/D: col=lane&15, row=(lane>>4)*4+reg
    int amax = 0;
#pragma unroll
    for (int mi = 0; mi < 8; ++mi) {
#pragma unroll
        for (int ni = 0; ni < 4; ++ni) {
            const int row0 = arow0 + (wr << 7) + (mi << 4) + (lk << 2);
            const int col  = brow0 + (wc << 6) + (ni << 4) + lr;
            i32x4 v = acc[mi][ni];
#pragma unroll
            for (int j = 0; j < 4; ++j) {
                C[(size_t)(row0 + j) * N_DIM + col] = v[j];
                int a = v[j] < 0 ? -v[j] : v[j];
                amax = max(amax, a);
            }
        }
    }
    for (int off = 32; off; off >>= 1)
        amax = max(amax, __shfl_xor(amax, off));
    if (ln == 0) wmax[wv] = amax;
    __syncthreads();
    if (t == 0) {
        int m = wmax[0];
#pragma unroll
        for (int i = 1; i < 8; ++i) m = max(m, wmax[i]);
        atomicMax(maxAcc, (unsigned)m);
    }
}

// ---------------- requantize int32 accum -> f32 output, in place ----------------
__global__ __launch_bounds__(256) void k_requant(int4* __restrict__ buf, int n4,
                                                 const unsigned* __restrict__ sc) {
    const float maxX = __uint_as_float(sc[0]);
    const float maxW = __uint_as_float(sc[1]);
    const float maxA = (float)(int)sc[2];
    const float in_scale = 127.0f / maxX;
    const float w_scale  = 127.0f / maxW;
    const float accum_scale = in_scale * w_scale;
    const float requant = 127.0f / maxA;
    const float out_scale = requant * accum_scale;
    int stride = gridDim.x * blockDim.x;
    for (int i = blockIdx.x * blockDim.x + threadIdx.x; i < n4; i += stride) {
        int4 v = buf[i];
        float4 o;
        o.x = fminf(127.f, fmaxf(-128.f, rintf((float)v.x * requant))) / out_scale;
        o.y = fminf(127.f, fmaxf(-128.f, rintf((float)v.y * requant))) / out_scale;
        o.z = fminf(127.f, fmaxf(-128.f, rintf((float)v.z * requant))) / out_scale;
        o.w = fminf(127.f, fmaxf(-128.f, rintf((float)v.w * requant))) / out_scale;
        ((float4*)buf)[i] = o;
    }
}

extern "C" void kernel_launch(void* const* d_in, const int* in_sizes, int n_in,
                              void* d_out, int out_size, void* d_ws, size_t ws_size,
                              hipStream_t stream) {
    const float* x = (const float*)d_in[0];  // [8192, 4096]
    const float* W = (const float*)d_in[1];  // [4096, 4096]

    unsigned* sc = (unsigned*)d_ws;
    char* xq = (char*)d_ws + 256;
    char* wq = xq + (size_t)M_DIM * K_DIM;

    hipMemsetAsync(sc, 0, 16, stream);  // sc[0..3] = 0 (replaces k_init launch)
    k_absmax2<<<3072, 256, 0, stream>>>((const float4*)x, (const float4*)W, sc);
    k_quant2<<<3072, 256, 0, stream>>>((const float4*)x, (const float4*)W,
                                       (uint4*)xq, (uint4*)wq, sc);
    k_gemm<<<(M_DIM / BM) * (N_DIM / BN), 512, 0, stream>>>(xq, wq, (int*)d_out, sc + 2);
    k_requant<<<2048, 256, 0, stream>>>((int4*)d_out, M_DIM * N_DIM / 4, sc);
}